// Round 4
// baseline (360.096 us; speedup 1.0000x reference)
//
#include <hip/hip_runtime.h>
#include <hip/hip_cooperative_groups.h>

namespace cg = cooperative_groups;

typedef unsigned int uint;
typedef unsigned short ushort;
typedef __attribute__((ext_vector_type(8))) short bf16x8;
typedef __attribute__((ext_vector_type(4))) float floatx4;
typedef __attribute__((ext_vector_type(4))) uint uint4v;

#define B_   64
#define NR_  16384
#define IC_  16
#define NC_  10
#define OC_  16
#define NCO  160   // NC_*OC_
#define KC_  32    // K chunks (512 r each)
#define KT_  32    // K tile per step

__device__ __forceinline__ float bf2f(ushort h) {
    return __uint_as_float(((uint)h) << 16);
}
__device__ __forceinline__ ushort f2bf(float f) {  // RNE
    uint u = __float_as_uint(f);
    u += 0x7fffu + ((u >> 16) & 1u);
    return (ushort)(u >> 16);
}
// split fp32 -> (hi, lo) bf16 pair; hi+lo captures f to ~2^-18 rel.
__device__ __forceinline__ void splitbf(float f, ushort& h, ushort& l) {
    h = f2bf(f);
    l = f2bf(f - bf2f(h));   // subtraction exact (operands within 2^-9)
}
// squash: s^2*s/((1+s^2)*sqrt(s^2)) == s*|s|/(1+s^2)
__device__ __forceinline__ float squashf(float s) {
    return s * fabsf(s) / (1.0f + s * s);
}

// ---------------------------------------------------------------------------
// Transpose+split: xTh/xTl[i][b][r] (bf16) from x[b][r][i] (fp32).
// grid (chunk=16, b=64), 256 thr. chunk==0 blocks also zero uh (+a1/a2 at
// b==0), replacing the separate memset dispatch.
// ---------------------------------------------------------------------------
__global__ __launch_bounds__(256) void k_xT(const float* __restrict__ xf,
                                            ushort* __restrict__ xTh,
                                            ushort* __restrict__ xTl,
                                            float* __restrict__ uh)
{
    const int chunk = blockIdx.x, b = blockIdx.y, t = threadIdx.x;
    if (chunk == 0) {   // zero this b's uh slice (2560 floats)
        float4 z = {0.f, 0.f, 0.f, 0.f};
        float4* dst = (float4*)(uh + (size_t)b * (IC_ * NCO));
        for (int n = t; n < 640; n += 256) dst[n] = z;
        if (b == 0 && t < 80) {   // zero a1+a2 (320 floats)
            float4* da = (float4*)(uh + (size_t)B_ * IC_ * NCO);
            da[t] = z;
        }
    }
    const int r0 = chunk * 1024;
#pragma unroll
    for (int j = 0; j < 4; ++j) {
        int r = r0 + t + 256 * j;
        const float* row = xf + ((size_t)b * NR_ + r) * IC_;
        float vals[16];
        *(float4*)&vals[0]  = *(const float4*)row;
        *(float4*)&vals[4]  = *(const float4*)(row + 4);
        *(float4*)&vals[8]  = *(const float4*)(row + 8);
        *(float4*)&vals[12] = *(const float4*)(row + 12);
#pragma unroll
        for (int i = 0; i < 16; ++i) {
            ushort h, l;
            splitbf(vals[i], h, l);
            size_t idx = ((size_t)(i * B_ + b)) * NR_ + r;
            xTh[idx] = h;
            xTl[idx] = l;
        }
    }
}

// ---------------------------------------------------------------------------
// u_hat[b][i][co] = sum_r W[i][co][r] * x[b][r][i]
// EXACT round-0 proven structure (321.8 us total):
// Split-bf16: u ~= xh*wh + xl*wh + xh*wl  (3 MFMAs, fp32 accum ~ fp32-exact).
// grid (i=16, kc=KC_), 512 thr (8 waves), 64(b) x 160(co) x 32(k) tiles.
// ---------------------------------------------------------------------------
__global__ __launch_bounds__(512) void k_uhat(const float* __restrict__ xf,
                                              const float* __restrict__ wf,
                                              const ushort* __restrict__ xTh,
                                              const ushort* __restrict__ xTl,
                                              int has_xt,
                                              float* __restrict__ uh)
{
    const int i    = blockIdx.x;
    const int kc   = blockIdx.y;
    const int tid  = threadIdx.x;
    const int lane = tid & 63;
    const int w    = tid >> 6;
    const int quad = lane >> 4;
    const int m16  = lane & 15;
    const int bt   = w & 3;    // b-tile (16 b's)
    const int cg_  = w >> 2;   // co-group (5 co-tiles each)

    // row stride 40 elems (80B): b128 frag reads are 2-way bank aliased (free)
    __shared__ ushort Xh[64 * 40], Xl[64 * 40];
    __shared__ ushort Wh[160 * 40], Wl[160 * 40];

    floatx4 acc[5];
#pragma unroll
    for (int t = 0; t < 5; ++t) acc[t] = (floatx4){0.f, 0.f, 0.f, 0.f};

    const int r0 = kc * (NR_ / KC_);

    for (int st = 0; st < (NR_ / KC_) / KT_; ++st) {
        const int rb = r0 + st * KT_;
        __syncthreads();
        // ---- stage X tiles (64 b x 32 k, hi+lo) ----
        if (has_xt) {
            int t8 = tid & 255, bb = t8 >> 2, part = t8 & 3;
            size_t src = (size_t)(i * B_ + bb) * NR_ + rb + part * 8;
            if (tid < 256)
                *(uint4v*)&Xh[bb * 40 + part * 8] = *(const uint4v*)&xTh[src];
            else
                *(uint4v*)&Xl[bb * 40 + part * 8] = *(const uint4v*)&xTl[src];
        } else {
#pragma unroll
            for (int s = 0; s < 4; ++s) {
                int n = tid + 512 * s;
                int bb = n >> 5, k = n & 31;
                float v = xf[(size_t)bb * (NR_ * IC_) + (size_t)(rb + k) * IC_ + i];
                ushort h, l;
                splitbf(v, h, l);
                Xh[bb * 40 + k] = h;
                Xl[bb * 40 + k] = l;
            }
        }
        // ---- stage W tiles (160 co x 32 k, fp32 -> hi+lo) ----
        for (int j = tid; j < 640; j += 512) {
            int row = j >> 2, seg = j & 3;
            const float* wp = wf + (size_t)(i * NCO + row) * NR_ + rb + seg * 8;
            float4 f0 = *(const float4*)wp;
            float4 f1 = *(const float4*)(wp + 4);
            float v[8] = {f0.x, f0.y, f0.z, f0.w, f1.x, f1.y, f1.z, f1.w};
            ushort hh[8], ll[8];
#pragma unroll
            for (int q = 0; q < 8; ++q) splitbf(v[q], hh[q], ll[q]);
            uint4v ph, pl;
#pragma unroll
            for (int q = 0; q < 4; ++q) {
                ph[q] = (uint)hh[2 * q] | ((uint)hh[2 * q + 1] << 16);
                pl[q] = (uint)ll[2 * q] | ((uint)ll[2 * q + 1] << 16);
            }
            *(uint4v*)&Wh[row * 40 + seg * 8] = ph;
            *(uint4v*)&Wl[row * 40 + seg * 8] = pl;
        }
        __syncthreads();
        // ---- MFMA: A[m=lane&15][k=quad*8+j]; B row = co, same k layout ----
        bf16x8 afh = *(const bf16x8*)&Xh[(bt * 16 + m16) * 40 + quad * 8];
        bf16x8 afl = *(const bf16x8*)&Xl[(bt * 16 + m16) * 40 + quad * 8];
#pragma unroll
        for (int t5 = 0; t5 < 5; ++t5) {
            int corow = (cg_ * 5 + t5) * 16 + m16;
            bf16x8 bh = *(const bf16x8*)&Wh[corow * 40 + quad * 8];
            bf16x8 bl = *(const bf16x8*)&Wl[corow * 40 + quad * 8];
            acc[t5] = __builtin_amdgcn_mfma_f32_16x16x32_bf16(afh, bh, acc[t5], 0, 0, 0);
            acc[t5] = __builtin_amdgcn_mfma_f32_16x16x32_bf16(afl, bh, acc[t5], 0, 0, 0);
            acc[t5] = __builtin_amdgcn_mfma_f32_16x16x32_bf16(afh, bl, acc[t5], 0, 0, 0);
        }
    }
    // epilogue: C/D col=lane&15 (co), row=quad*4+reg (b in tile)
#pragma unroll
    for (int t5 = 0; t5 < 5; ++t5) {
        int co = (cg_ * 5 + t5) * 16 + m16;
#pragma unroll
        for (int r = 0; r < 4; ++r) {
            int b = bt * 16 + quad * 4 + r;
            atomicAdd(&uh[(b * IC_ + i) * NCO + co], acc[t5][r]);
        }
    }
}

// ---------------------------------------------------------------------------
// Cooperative routing: the THREE round-0 route kernels (own-b work + tiny
// global atomics -- NO redundant full-batch recompute) separated by
// grid.sync() instead of kernel boundaries. 64 blocks x 256 thr.
// out (fp32): [0:64) pred, [64:10304) v3[b][c][o].
// ---------------------------------------------------------------------------
__global__ __launch_bounds__(256) void k_route_coop(const float* __restrict__ uh,
                                                    float* __restrict__ a1,
                                                    float* __restrict__ a2,
                                                    const float* __restrict__ fcw,
                                                    const float* __restrict__ fcb,
                                                    float* __restrict__ out)
{
    cg::grid_group grid = cg::this_grid();
    const int b = blockIdx.x, tid = threadIdx.x;
    __shared__ float vL[NCO];
    __shared__ float aL[NCO];
    const float* ub = uh + b * IC_ * NCO;

    // ======== phase 1 (== round-0 k_route1) ========
    if (tid < NCO) {
        float s = 0.f;
#pragma unroll
        for (int i = 0; i < IC_; ++i) s += ub[i * NCO + tid];
        vL[tid] = squashf(s * (1.0f / 16.0f));
    }
    __syncthreads();
    if (tid < NCO) {
        int i = tid / NC_, c = tid - i * NC_;
        float sum = 0.f;
#pragma unroll
        for (int o = 0; o < OC_; ++o)
            sum += ub[i * NCO + c * OC_ + o] * vL[c * OC_ + o];
        atomicAdd(&a1[i * NC_ + c], sum * (1.0f / 64.0f));
    }
    __threadfence();
    grid.sync();

    // ======== phase 2 (== round-0 k_route2) ========
    if (tid < NCO) aL[tid] = a1[tid];
    __syncthreads();
    if (tid < NCO) {
        int c = tid >> 4;
        float m = -1e30f;
#pragma unroll
        for (int i = 0; i < IC_; ++i) m = fmaxf(m, aL[i * NC_ + c]);
        float Z = 0.f;
#pragma unroll
        for (int i = 0; i < IC_; ++i) Z += expf(aL[i * NC_ + c] - m);
        float s = 0.f;
        for (int i = 0; i < IC_; ++i)
            s += (expf(aL[i * NC_ + c] - m) / Z) * ub[i * NCO + tid];
        vL[tid] = squashf(s);
    }
    __syncthreads();
    if (tid < NCO) {
        int i = tid / NC_, c = tid - i * NC_;
        float sum = 0.f;
#pragma unroll
        for (int o = 0; o < OC_; ++o)
            sum += ub[i * NCO + c * OC_ + o] * vL[c * OC_ + o];
        atomicAdd(&a2[i * NC_ + c], sum * (1.0f / 64.0f));
    }
    __threadfence();
    grid.sync();

    // ======== phase 3 (== round-0 k_route3) ========
    if (tid < NCO) aL[tid] = a1[tid] + a2[tid];
    __syncthreads();
    if (tid < NCO) {
        int c = tid >> 4;
        float m = -1e30f;
#pragma unroll
        for (int i = 0; i < IC_; ++i) m = fmaxf(m, aL[i * NC_ + c]);
        float Z = 0.f;
#pragma unroll
        for (int i = 0; i < IC_; ++i) Z += expf(aL[i * NC_ + c] - m);
        float s = 0.f;
        for (int i = 0; i < IC_; ++i)
            s += (expf(aL[i * NC_ + c] - m) / Z) * ub[i * NCO + tid];
        float v = squashf(s);
        out[64 + b * NCO + tid] = v;
        vL[tid] = v * fcw[tid];          // reuse vL as FC partials
    }
    __syncthreads();
    if (tid == 0) {
        float a = fcb[0];
        for (int j = 0; j < NCO; ++j) a += vL[j];
        out[b] = 1.0f / (1.0f + expf(-a));
    }
}

extern "C" void kernel_launch(void* const* d_in, const int* in_sizes, int n_in,
                              void* d_out, int out_size, void* d_ws, size_t ws_size,
                              hipStream_t stream)
{
    const float* x   = (const float*)d_in[0];
    const float* W   = (const float*)d_in[1];
    const float* fcw = (const float*)d_in[2];
    const float* fcb = (const float*)d_in[3];
    float* out = (float*)d_out;

    float* uh = (float*)d_ws;                      // 163840 fp32
    float* a1 = uh + B_ * IC_ * NCO;               // 160 fp32
    float* a2 = a1 + NCO;                          // 160 fp32
    const size_t xt_off   = 1u << 20;              // 1 MB
    const size_t xt_bytes = (size_t)IC_ * B_ * NR_ * 2;  // 33.5 MB per plane
    ushort* xTh = (ushort*)((char*)d_ws + xt_off);
    ushort* xTl = (ushort*)((char*)d_ws + xt_off + xt_bytes);
    const int has_xt = (ws_size >= xt_off + 2 * xt_bytes) ? 1 : 0;  // host-const

    if (has_xt) {
        k_xT<<<dim3(16, 64), 256, 0, stream>>>(x, xTh, xTl, uh);   // also zeroes uh/a1/a2
    } else {
        hipMemsetAsync(d_ws, 0, (size_t)(B_ * IC_ * NCO + 2 * NCO) * sizeof(float), stream);
    }
    k_uhat<<<dim3(IC_, KC_), 512, 0, stream>>>(x, W, xTh, xTl, has_xt, uh);

    void* args[] = {(void*)&uh, (void*)&a1, (void*)&a2,
                    (void*)&fcw, (void*)&fcb, (void*)&out};
    hipLaunchCooperativeKernel((void*)k_route_coop, dim3(B_), dim3(256), args, 0, stream);
}

// Round 6
// 318.345 us; speedup vs baseline: 1.1312x; 1.1312x over previous
//
#include <hip/hip_runtime.h>

typedef unsigned int uint;
typedef unsigned short ushort;
typedef __attribute__((ext_vector_type(8))) short bf16x8;
typedef __attribute__((ext_vector_type(4))) float floatx4;
typedef __attribute__((ext_vector_type(4))) uint uint4v;
typedef __attribute__((ext_vector_type(2))) float floatx2;
typedef __attribute__((ext_vector_type(2))) __bf16 bfx2;

#define B_   64
#define NR_  16384
#define IC_  16
#define NC_  10
#define OC_  16
#define NCO  160   // NC_*OC_
#define KC_  32    // K chunks (512 r each)
#define KT_  32    // K tile per step

__device__ __forceinline__ float bf2f(ushort h) {
    return __uint_as_float(((uint)h) << 16);
}
__device__ __forceinline__ ushort f2bf(float f) {  // RNE (bit trick, fallback path)
    uint u = __float_as_uint(f);
    u += 0x7fffu + ((u >> 16) & 1u);
    return (ushort)(u >> 16);
}
// split fp32 -> (hi, lo) bf16 pair; hi+lo captures f to ~2^-18 rel. (fallback)
__device__ __forceinline__ void splitbf(float f, ushort& h, ushort& l) {
    h = f2bf(f);
    l = f2bf(f - bf2f(h));   // subtraction exact (operands within 2^-9)
}
// Pairwise split via HW v_cvt_pk_bf16_f32 (RNE, bit-identical to bit trick).
// Returns {hi_pair, lo_pair} packed as 2x bf16 in each uint.
__device__ __forceinline__ uint2 cvt2(float a, float b)
{
    floatx2 f = {a, b};
    bfx2 h  = __builtin_convertvector(f, bfx2);     // v_cvt_pk_bf16_f32
    floatx2 hf = __builtin_convertvector(h, floatx2);
    floatx2 r = f - hf;                              // exact
    bfx2 l  = __builtin_convertvector(r, bfx2);
    uint2 out;
    out.x = __builtin_bit_cast(uint, h);
    out.y = __builtin_bit_cast(uint, l);
    return out;
}
// squash: s^2*s/((1+s^2)*sqrt(s^2)) == s*|s|/(1+s^2)
__device__ __forceinline__ float squashf(float s) {
    return s * fabsf(s) / (1.0f + s * s);
}

// ---------------------------------------------------------------------------
// Transpose+split: xTh/xTl[i][b][r] (bf16) from x[b][r][i] (fp32).
// grid (chunk=16, b=64), 256 thr; each thread: 4 r's x 16 i's.
// ---------------------------------------------------------------------------
__global__ __launch_bounds__(256) void k_xT(const float* __restrict__ xf,
                                            ushort* __restrict__ xTh,
                                            ushort* __restrict__ xTl)
{
    const int chunk = blockIdx.x, b = blockIdx.y, t = threadIdx.x;
    const int r0 = chunk * 1024;
#pragma unroll
    for (int j = 0; j < 4; ++j) {
        int r = r0 + t + 256 * j;
        const float* row = xf + ((size_t)b * NR_ + r) * IC_;
        float vals[16];
        *(float4*)&vals[0]  = *(const float4*)row;
        *(float4*)&vals[4]  = *(const float4*)(row + 4);
        *(float4*)&vals[8]  = *(const float4*)(row + 8);
        *(float4*)&vals[12] = *(const float4*)(row + 12);
#pragma unroll
        for (int i = 0; i < 16; i += 2) {
            uint2 hl = cvt2(vals[i], vals[i + 1]);
            size_t idx0 = ((size_t)(i * B_ + b)) * NR_ + r;
            size_t idx1 = ((size_t)((i + 1) * B_ + b)) * NR_ + r;
            xTh[idx0] = (ushort)hl.x;  xTh[idx1] = (ushort)(hl.x >> 16);
            xTl[idx0] = (ushort)hl.y;  xTl[idx1] = (ushort)(hl.y >> 16);
        }
    }
}

// ---------------------------------------------------------------------------
// u_hat[b][i][co] = sum_r W[i][co][r] * x[b][r][i]
// Split-bf16: u ~= xh*wh + xl*wh + xh*wl  (3 MFMAs, fp32 accum ~ fp32-exact).
// grid (i=16, kc=KC_), 512 thr (8 waves), 64(b) x 160(co) x 32(k) tiles.
// Round-0 proven structure; only the W fp32->bf16hi/lo convert now uses
// HW v_cvt_pk_bf16_f32 pairs (VALU cut ~3x; numerics bit-identical RNE).
// ---------------------------------------------------------------------------
__global__ __launch_bounds__(512) void k_uhat(const float* __restrict__ xf,
                                              const float* __restrict__ wf,
                                              const ushort* __restrict__ xTh,
                                              const ushort* __restrict__ xTl,
                                              int has_xt,
                                              float* __restrict__ uh)
{
    const int i    = blockIdx.x;
    const int kc   = blockIdx.y;
    const int tid  = threadIdx.x;
    const int lane = tid & 63;
    const int w    = tid >> 6;
    const int quad = lane >> 4;
    const int m16  = lane & 15;
    const int bt   = w & 3;    // b-tile (16 b's)
    const int cg   = w >> 2;   // co-group (5 co-tiles each)

    // row stride 40 elems (80B): b128 frag reads are 2-way bank aliased (free)
    __shared__ ushort Xh[64 * 40], Xl[64 * 40];
    __shared__ ushort Wh[160 * 40], Wl[160 * 40];

    floatx4 acc[5];
#pragma unroll
    for (int t = 0; t < 5; ++t) acc[t] = (floatx4){0.f, 0.f, 0.f, 0.f};

    const int r0 = kc * (NR_ / KC_);

    for (int st = 0; st < (NR_ / KC_) / KT_; ++st) {
        const int rb = r0 + st * KT_;
        __syncthreads();
        // ---- stage X tiles (64 b x 32 k, hi+lo) ----
        if (has_xt) {
            int t8 = tid & 255, bb = t8 >> 2, part = t8 & 3;
            size_t src = (size_t)(i * B_ + bb) * NR_ + rb + part * 8;
            if (tid < 256)
                *(uint4v*)&Xh[bb * 40 + part * 8] = *(const uint4v*)&xTh[src];
            else
                *(uint4v*)&Xl[bb * 40 + part * 8] = *(const uint4v*)&xTl[src];
        } else {
#pragma unroll
            for (int s = 0; s < 4; ++s) {
                int n = tid + 512 * s;
                int bb = n >> 5, k = n & 31;
                float v = xf[(size_t)bb * (NR_ * IC_) + (size_t)(rb + k) * IC_ + i];
                ushort h, l;
                splitbf(v, h, l);
                Xh[bb * 40 + k] = h;
                Xl[bb * 40 + k] = l;
            }
        }
        // ---- stage W tiles (160 co x 32 k, fp32 -> hi+lo via cvt_pk) ----
        for (int j = tid; j < 640; j += 512) {
            int row = j >> 2, seg = j & 3;
            const float* wp = wf + (size_t)(i * NCO + row) * NR_ + rb + seg * 8;
            float4 f0 = *(const float4*)wp;
            float4 f1 = *(const float4*)(wp + 4);
            uint2 p0 = cvt2(f0.x, f0.y);
            uint2 p1 = cvt2(f0.z, f0.w);
            uint2 p2 = cvt2(f1.x, f1.y);
            uint2 p3 = cvt2(f1.z, f1.w);
            uint4v ph, pl;
            ph[0] = p0.x; ph[1] = p1.x; ph[2] = p2.x; ph[3] = p3.x;
            pl[0] = p0.y; pl[1] = p1.y; pl[2] = p2.y; pl[3] = p3.y;
            *(uint4v*)&Wh[row * 40 + seg * 8] = ph;
            *(uint4v*)&Wl[row * 40 + seg * 8] = pl;
        }
        __syncthreads();
        // ---- MFMA: A[m=lane&15][k=quad*8+j]; B row = co, same k layout ----
        bf16x8 afh = *(const bf16x8*)&Xh[(bt * 16 + m16) * 40 + quad * 8];
        bf16x8 afl = *(const bf16x8*)&Xl[(bt * 16 + m16) * 40 + quad * 8];
#pragma unroll
        for (int t5 = 0; t5 < 5; ++t5) {
            int corow = (cg * 5 + t5) * 16 + m16;
            bf16x8 bh = *(const bf16x8*)&Wh[corow * 40 + quad * 8];
            bf16x8 bl = *(const bf16x8*)&Wl[corow * 40 + quad * 8];
            acc[t5] = __builtin_amdgcn_mfma_f32_16x16x32_bf16(afh, bh, acc[t5], 0, 0, 0);
            acc[t5] = __builtin_amdgcn_mfma_f32_16x16x32_bf16(afl, bh, acc[t5], 0, 0, 0);
            acc[t5] = __builtin_amdgcn_mfma_f32_16x16x32_bf16(afh, bl, acc[t5], 0, 0, 0);
        }
    }
    // epilogue: C/D col=lane&15 (co), row=quad*4+reg (b in tile)
#pragma unroll
    for (int t5 = 0; t5 < 5; ++t5) {
        int co = (cg * 5 + t5) * 16 + m16;
#pragma unroll
        for (int r = 0; r < 4; ++r) {
            int b = bt * 16 + quad * 4 + r;
            atomicAdd(&uh[(b * IC_ + i) * NCO + co], acc[t5][r]);
        }
    }
}

// ---------------------------------------------------------------------------
// Routing iter 1 (uniform c): v1 -> partial a1[i][c]
// ---------------------------------------------------------------------------
__global__ __launch_bounds__(256) void k_route1(const float* __restrict__ uh,
                                                float* __restrict__ a1)
{
    const int b = blockIdx.x, tid = threadIdx.x;
    __shared__ float vL[NCO];
    const float* ub = uh + b * IC_ * NCO;
    if (tid < NCO) {
        float s = 0.f;
#pragma unroll
        for (int i = 0; i < IC_; ++i) s += ub[i * NCO + tid];
        vL[tid] = squashf(s * (1.0f / 16.0f));
    }
    __syncthreads();
    if (tid < NCO) {
        int i = tid / NC_, c = tid - i * NC_;
        float sum = 0.f;
#pragma unroll
        for (int o = 0; o < OC_; ++o)
            sum += ub[i * NCO + c * OC_ + o] * vL[c * OC_ + o];
        atomicAdd(&a1[i * NC_ + c], sum * (1.0f / 64.0f));
    }
}

// ---------------------------------------------------------------------------
// Routing iter 2: c = softmax_i(a1); v2 -> partial a2[i][c]
// ---------------------------------------------------------------------------
__global__ __launch_bounds__(256) void k_route2(const float* __restrict__ uh,
                                                const float* __restrict__ a1,
                                                float* __restrict__ a2)
{
    const int b = blockIdx.x, tid = threadIdx.x;
    __shared__ float aL[NCO];
    __shared__ float vL[NCO];
    if (tid < NCO) aL[tid] = a1[tid];
    __syncthreads();
    const float* ub = uh + b * IC_ * NCO;
    if (tid < NCO) {
        int c = tid >> 4;
        float m = -1e30f;
        for (int i = 0; i < IC_; ++i) m = fmaxf(m, aL[i * NC_ + c]);
        float Z = 0.f;
        for (int i = 0; i < IC_; ++i) Z += expf(aL[i * NC_ + c] - m);
        float s = 0.f;
        for (int i = 0; i < IC_; ++i)
            s += (expf(aL[i * NC_ + c] - m) / Z) * ub[i * NCO + tid];
        vL[tid] = squashf(s);
    }
    __syncthreads();
    if (tid < NCO) {
        int i = tid / NC_, c = tid - i * NC_;
        float sum = 0.f;
#pragma unroll
        for (int o = 0; o < OC_; ++o)
            sum += ub[i * NCO + c * OC_ + o] * vL[c * OC_ + o];
        atomicAdd(&a2[i * NC_ + c], sum * (1.0f / 64.0f));
    }
}

// ---------------------------------------------------------------------------
// Routing iter 3 + FC head. out (fp32): [0:64) pred, [64:10304) v3[b][c][o].
// ---------------------------------------------------------------------------
__global__ __launch_bounds__(256) void k_route3(const float* __restrict__ uh,
                                                const float* __restrict__ a1,
                                                const float* __restrict__ a2,
                                                const float* __restrict__ fcw,
                                                const float* __restrict__ fcb,
                                                float* __restrict__ out)
{
    const int b = blockIdx.x, tid = threadIdx.x;
    __shared__ float bL[NCO];
    __shared__ float pL[NCO];
    if (tid < NCO) bL[tid] = a1[tid] + a2[tid];
    __syncthreads();
    const float* ub = uh + b * IC_ * NCO;
    if (tid < NCO) {
        int c = tid >> 4;
        float m = -1e30f;
        for (int i = 0; i < IC_; ++i) m = fmaxf(m, bL[i * NC_ + c]);
        float Z = 0.f;
        for (int i = 0; i < IC_; ++i) Z += expf(bL[i * NC_ + c] - m);
        float s = 0.f;
        for (int i = 0; i < IC_; ++i)
            s += (expf(bL[i * NC_ + c] - m) / Z) * ub[i * NCO + tid];
        float v = squashf(s);
        out[64 + b * NCO + tid] = v;
        pL[tid] = v * fcw[tid];
    }
    __syncthreads();
    if (tid == 0) {
        float accv = fcb[0];
        for (int j = 0; j < NCO; ++j) accv += pL[j];
        out[b] = 1.0f / (1.0f + expf(-accv));
    }
}

extern "C" void kernel_launch(void* const* d_in, const int* in_sizes, int n_in,
                              void* d_out, int out_size, void* d_ws, size_t ws_size,
                              hipStream_t stream)
{
    const float* x   = (const float*)d_in[0];
    const float* W   = (const float*)d_in[1];
    const float* fcw = (const float*)d_in[2];
    const float* fcb = (const float*)d_in[3];
    float* out = (float*)d_out;

    float* uh = (float*)d_ws;                      // 163840 fp32
    float* a1 = uh + B_ * IC_ * NCO;               // 160 fp32
    float* a2 = a1 + NCO;                          // 160 fp32
    const size_t xt_off   = 1u << 20;              // 1 MB
    const size_t xt_bytes = (size_t)IC_ * B_ * NR_ * 2;  // 33.5 MB per plane
    ushort* xTh = (ushort*)((char*)d_ws + xt_off);
    ushort* xTl = (ushort*)((char*)d_ws + xt_off + xt_bytes);
    const int has_xt = (ws_size >= xt_off + 2 * xt_bytes) ? 1 : 0;  // host-const

    (void)hipMemsetAsync(d_ws, 0, (size_t)(B_ * IC_ * NCO + 2 * NCO) * sizeof(float), stream);
    if (has_xt)
        k_xT<<<dim3(16, 64), 256, 0, stream>>>(x, xTh, xTl);
    k_uhat<<<dim3(IC_, KC_), 512, 0, stream>>>(x, W, xTh, xTl, has_xt, uh);
    k_route1<<<B_, 256, 0, stream>>>(uh, a1);
    k_route2<<<B_, 256, 0, stream>>>(uh, a1, a2);
    k_route3<<<B_, 256, 0, stream>>>(uh, a1, a2, fcw, fcb, out);
}